// Round 1
// baseline (241.819 us; speedup 1.0000x reference)
//
#include <hip/hip_runtime.h>

#define NEGV -100000.0f

__constant__ int c_perm_table[3][16] = {
  {0,1,2,3,4,5,6,7,8,9,10,11,12,13,14,15},
  {4,5,6,7,8,9,10,11,0,1,2,3,12,13,14,15},
  {8,9,10,11,12,13,14,15,0,1,2,3,4,5,6,7}
};

// ---- Kernel 1: fea_map channel-group partial sums (deterministic, no atomics)
// grid = B*16 blocks, 256 threads. Block (b,g) sums channels [g*64, g*64+64) per pixel.
__global__ void k_cm(const float* __restrict__ fea, float* __restrict__ partial) {
  int bid = blockIdx.x;
  int b = bid >> 4, g = bid & 15;
  const float* src = fea + ((size_t)(b * 1024 + g * 64)) * 784;
  int t = threadIdx.x;
  float a0 = 0.f, a1 = 0.f, a2 = 0.f, a3 = 0.f;
  for (int cc = 0; cc < 64; ++cc) {
    const float* row = src + (size_t)cc * 784;
    a0 += row[t];
    a1 += row[t + 256];
    a2 += row[t + 512];
    if (t < 16) a3 += row[t + 768];
  }
  float* dst = partial + (size_t)(b * 16 + g) * 784;
  dst[t] = a0; dst[t + 256] = a1; dst[t + 512] = a2;
  if (t < 16) dst[t + 768] = a3;
}

// ---- Kernel 2: finish mean, 4x4 cells, area argmax, write perms (as float) to d_out tail
__global__ void k_perm(const float* __restrict__ partial, float* __restrict__ out_perms) {
  __shared__ float pix[784];
  __shared__ float cells[16];
  int b = blockIdx.x, t = threadIdx.x;
  const float* part = partial + (size_t)b * 16 * 784;
  for (int q = 0; q < 4; ++q) {
    int p = t + q * 256;
    if (p < 784) {
      float s = 0.f;
      for (int g = 0; g < 16; ++g) s += part[g * 784 + p];
      pix[p] = s;
    }
  }
  __syncthreads();
  if (t < 16) {
    int ci = t >> 2, cj = t & 3;
    float s = 0.f;
    for (int dy = 0; dy < 7; ++dy)
      for (int dx = 0; dx < 7; ++dx)
        s += pix[(ci * 7 + dy) * 28 + cj * 7 + dx];
    cells[t] = s * (1.0f / (1024.f * 49.f));
  }
  __syncthreads();
  if (t == 0) {
    float s0 = 0.f, s1 = 0.f, s2 = 0.f;
    for (int k = 0; k < 8; ++k)  s0 += cells[k];
    for (int k = 4; k < 12; ++k) s1 += cells[k];
    for (int k = 8; k < 16; ++k) s2 += cells[k];
    int area = 0; float best = s0;
    if (s1 > best) { best = s1; area = 1; }
    if (s2 > best) { best = s2; area = 2; }
    for (int k = 0; k < 16; ++k) out_perms[b * 16 + k] = (float)c_perm_table[area][k];
  }
}

// ---- Kernel 3: softmax + 32-step peel, one wave per batch. Lane l owns row l>>1,
// cols (l&1)*16..+15. All reductions are shfl_xor (rows vary with masks 2..32).
// Writes bsum into result_centre output slot: result_centre[B-1-b][c] = r[b].
__global__ void k_peel(const float* __restrict__ params, const int* __restrict__ pseq,
                       const int* __restrict__ pbsz, float* __restrict__ out_rc, int B) {
  int b = blockIdx.x, l = threadIdx.x;
  int start = pseq[0] * pbsz[0];
  int r0 = l >> 1, hi = l & 1;
  const float* Pp = params + ((size_t)(start + b)) * 1024 + r0 * 32 + hi * 16;
  float v[16];
  #pragma unroll
  for (int j = 0; j < 16; ++j) v[j] = Pp[j];
  // softmax over rows (axis=1) per column
  float m[16];
  #pragma unroll
  for (int j = 0; j < 16; ++j) m[j] = v[j];
  #pragma unroll
  for (int s = 0; s < 5; ++s) {
    int mask = 2 << s;
    #pragma unroll
    for (int j = 0; j < 16; ++j) m[j] = fmaxf(m[j], __shfl_xor(m[j], mask, 64));
  }
  float e[16], ssum[16];
  #pragma unroll
  for (int j = 0; j < 16; ++j) { e[j] = expf(v[j] - m[j]); ssum[j] = e[j]; }
  #pragma unroll
  for (int s = 0; s < 5; ++s) {
    int mask = 2 << s;
    #pragma unroll
    for (int j = 0; j < 16; ++j) ssum[j] += __shfl_xor(ssum[j], mask, 64);
  }
  #pragma unroll
  for (int j = 0; j < 16; ++j) v[j] = e[j] / ssum[j];

  float bsum[16];
  #pragma unroll
  for (int j = 0; j < 16; ++j) bsum[j] = 0.f;
  int base = r0 * 32 + hi * 16;

  for (int it = 0; it < 32; ++it) {
    // global max + argmax (flat row-major index)
    float bv = v[0]; int bi = base;
    #pragma unroll
    for (int j = 1; j < 16; ++j) { if (v[j] > bv) { bv = v[j]; bi = base + j; } }
    #pragma unroll
    for (int s = 0; s < 6; ++s) {
      int mask = 1 << s;
      float ov = __shfl_xor(bv, mask, 64);
      int   oi = __shfl_xor(bi, mask, 64);
      if (ov > bv || (ov == bv && oi < bi)) { bv = ov; bi = oi; }
    }
    float maxv = bv; int amax = bi;
    // second max (exclude the single argmax instance)
    float m2 = -3.4e38f;
    #pragma unroll
    for (int j = 0; j < 16; ++j) {
      float vv = (base + j == amax) ? -3.4e38f : v[j];
      m2 = fmaxf(m2, vv);
    }
    #pragma unroll
    for (int s = 0; s < 6; ++s) m2 = fmaxf(m2, __shfl_xor(m2, 1 << s, 64));

    float mid = (maxv + m2) * 0.5f;
    float hg  = (maxv - m2) * 0.5f;
    float bj[16];
    #pragma unroll
    for (int j = 0; j < 16; ++j) bj[j] = fmaxf(v[j] - mid, 0.f) / hg;
    float bm = bj[0];
    #pragma unroll
    for (int j = 1; j < 16; ++j) bm = fmaxf(bm, bj[j]);
    #pragma unroll
    for (int s = 0; s < 6; ++s) bm = fmaxf(bm, __shfl_xor(bm, 1 << s, 64));
    float rs = 0.f;
    #pragma unroll
    for (int j = 0; j < 16; ++j) { bj[j] = bj[j] / bm; bsum[j] += bj[j]; rs += bj[j]; }
    rs += __shfl_xor(rs, 1, 64);  // partner lane: other half of same row
    float cs[16];
    #pragma unroll
    for (int j = 0; j < 16; ++j) cs[j] = bj[j];
    #pragma unroll
    for (int s = 0; s < 5; ++s) {
      int mask = 2 << s;
      #pragma unroll
      for (int j = 0; j < 16; ++j) cs[j] += __shfl_xor(cs[j], mask, 64);
    }
    #pragma unroll
    for (int j = 0; j < 16; ++j) v[j] += NEGV * (rs + cs[j]);
  }
  int bo = B - 1 - b;
  #pragma unroll
  for (int c = 0; c < 3; ++c) {
    float* dst = out_rc + ((size_t)(bo * 3 + c)) * 1024 + base;
    #pragma unroll
    for (int j = 0; j < 16; ++j) dst[j] = bsum[j];
  }
}

// ---- Kernel 4: centre mix. Each of the 32 output 56x56 sub-blocks is a linear
// combination of the 32 input sub-blocks with weights R[n][m] = result_centre[b].
// sbase[] gives the (identical-form) in/out sub-block base offset in the image.
// grid = B*3*49 blocks, 256 threads; each block handles 64 pixel positions.
__global__ void k_centre(const float* __restrict__ x, float* __restrict__ out,
                         const float* __restrict__ rc, const float* __restrict__ permsf) {
  __shared__ float Rl[1024];
  __shared__ float inT[2048];
  __shared__ int sbase[32];
  int bid = blockIdx.x;
  int tile = bid % 49;
  int bc = bid / 49;
  int c = bc % 3;
  int b = bc / 3;
  int t = threadIdx.x;
  const float* Rsrc = rc + (size_t)b * 3 * 1024;  // result_centre[b][0] == r[B-1-b]
  #pragma unroll
  for (int q = 0; q < 4; ++q) Rl[t + q * 256] = Rsrc[t + q * 256];
  if (t < 32) {
    int n = t, rn = n >> 3, sn = n & 7;
    int kp = (rn >> 1) * 4 + (sn >> 1);
    int tp = (int)permsf[b * 16 + kp];
    int Y0 = (tp >> 2) * 112 + (rn & 1) * 56;
    int X0 = (tp & 3) * 112 + (sn & 1) * 56;
    sbase[n] = Y0 * 448 + X0;
  }
  __syncthreads();
  size_t base_bc = (size_t)(b * 3 + c) * 200704;
  #pragma unroll
  for (int q = 0; q < 8; ++q) {
    int e = t + q * 256;
    int n = e >> 6, pl = e & 63;
    int p = tile * 64 + pl;
    int i2 = p / 56, j2 = p - i2 * 56;
    inT[e] = x[base_bc + sbase[n] + i2 * 448 + j2];
  }
  __syncthreads();
  int mg = t >> 6, pl = t & 63;
  int p = tile * 64 + pl;
  int i2 = p / 56, j2 = p - i2 * 56;
  float acc[8];
  #pragma unroll
  for (int q = 0; q < 8; ++q) acc[q] = 0.f;
  #pragma unroll 4
  for (int n = 0; n < 32; ++n) {
    float xv = inT[n * 64 + pl];
    #pragma unroll
    for (int q = 0; q < 8; ++q) acc[q] += Rl[n * 32 + mg * 8 + q] * xv;
  }
  int pofs = i2 * 448 + j2;
  #pragma unroll
  for (int q = 0; q < 8; ++q) out[base_bc + sbase[mg * 8 + q] + pofs] = acc[q];
}

// ---- Kernel 5: boundary patches pass through unchanged (same coordinates).
// grid = B*3*8 blocks, 256 threads. Patch = perms[8+kk].
__global__ void k_boundary(const float* __restrict__ x, float* __restrict__ out,
                           const float* __restrict__ permsf) {
  int bid = blockIdx.x;
  int kk = bid & 7;
  int c = (bid >> 3) % 3;
  int b = bid / 24;
  int tp = (int)permsf[b * 16 + 8 + kk];
  size_t base = (size_t)(b * 3 + c) * 200704 + (size_t)((tp >> 2) * 112) * 448 + (tp & 3) * 112;
  int t = threadIdx.x;
  #pragma unroll 7
  for (int q = 0; q < 49; ++q) {
    int e = t + q * 256;
    int i = e / 112, j = e - i * 112;
    size_t a = base + (size_t)i * 448 + j;
    out[a] = x[a];
  }
}

extern "C" void kernel_launch(void* const* d_in, const int* in_sizes, int n_in,
                              void* d_out, int out_size, void* d_ws, size_t ws_size,
                              hipStream_t stream) {
  const float* x      = (const float*)d_in[0];
  const float* fea    = (const float*)d_in[1];
  const float* params = (const float*)d_in[2];
  const int*   bseq   = (const int*)d_in[3];
  const int*   bsz    = (const int*)d_in[4];
  float* out = (float*)d_out;

  int B = in_sizes[0] / (3 * 448 * 448);           // 64
  size_t RC_OFF   = (size_t)B * 3 * 448 * 448;     // x_out elements
  size_t PERM_OFF = RC_OFF + (size_t)B * 3 * 32 * 32;

  // Scratch for channel-group partials lives at the front of d_out's x_out slot;
  // it is consumed by k_perm before k_centre/k_boundary fully overwrite x_out.
  float* partial = out;

  hipLaunchKernelGGL(k_cm,       dim3(B * 16),     dim3(256), 0, stream, fea, partial);
  hipLaunchKernelGGL(k_perm,     dim3(B),          dim3(256), 0, stream, partial, out + PERM_OFF);
  hipLaunchKernelGGL(k_peel,     dim3(B),          dim3(64),  0, stream, params, bseq, bsz, out + RC_OFF, B);
  hipLaunchKernelGGL(k_centre,   dim3(B * 3 * 49), dim3(256), 0, stream, x, out, out + RC_OFF, out + PERM_OFF);
  hipLaunchKernelGGL(k_boundary, dim3(B * 24),     dim3(256), 0, stream, x, out, out + PERM_OFF);
}

// Round 3
// 139.386 us; speedup vs baseline: 1.7349x; 1.7349x over previous
//
#include <hip/hip_runtime.h>

__constant__ int c_perm_table[3][16] = {
  {0,1,2,3,4,5,6,7,8,9,10,11,12,13,14,15},
  {4,5,6,7,8,9,10,11,0,1,2,3,12,13,14,15},
  {8,9,10,11,12,13,14,15,0,1,2,3,4,5,6,7}
};

// ---- K1 (fused): blocks [0, B*16) do fea channel-group cell partial sums;
//      blocks [B*16, B*16+B) do the greedy peel (softmax + 32x masked argmax).
// Peel writes result_centre (exact 0/1 permutation matrix, batch-reversed) and
// src table (ALSO batch-reversed, so k3 can index by image batch directly).
__global__ void k1_fused(const float* __restrict__ fea, const float* __restrict__ params,
                         const int* __restrict__ pseq, const int* __restrict__ pbsz,
                         float* __restrict__ partial, int* __restrict__ src_t,
                         float* __restrict__ out_rc, int B) {
  int bid = blockIdx.x;
  if (bid < (B << 4)) {
    // --- fea_map: sum 64 channels per pixel, reduce to 16 cell sums ---
    __shared__ float pix[784];
    int b = bid >> 4, g = bid & 15;
    const float* src = fea + ((size_t)(b * 1024 + g * 64)) * 784;
    int t = threadIdx.x;
    float a0 = 0.f, a1 = 0.f, a2 = 0.f, a3 = 0.f;
    for (int cc = 0; cc < 64; ++cc) {
      const float* row = src + (size_t)cc * 784;
      a0 += row[t];
      a1 += row[t + 256];
      a2 += row[t + 512];
      if (t < 16) a3 += row[t + 768];
    }
    pix[t] = a0; pix[t + 256] = a1; pix[t + 512] = a2;
    if (t < 16) pix[t + 768] = a3;
    __syncthreads();
    if (t < 16) {
      int ci = t >> 2, cj = t & 3;
      float s = 0.f;
      for (int dy = 0; dy < 7; ++dy)
        for (int dx = 0; dx < 7; ++dx)
          s += pix[(ci * 7 + dy) * 28 + cj * 7 + dx];
      partial[(b * 16 + g) * 16 + t] = s;
    }
    return;
  }
  // --- greedy peel: one wave per batch ---
  int b = bid - (B << 4);
  int l = threadIdx.x;
  if (l >= 64) return;
  int start = pseq[0] * pbsz[0];
  int r0 = l >> 1, hi = l & 1;
  int base = r0 * 32 + hi * 16;
  const float* Pp = params + ((size_t)(start + b)) * 1024 + base;
  float v[16];
  #pragma unroll
  for (int j = 0; j < 16; ++j) v[j] = Pp[j];
  // column softmax (reduce over rows = lane bits 1..5)
  float m[16];
  #pragma unroll
  for (int j = 0; j < 16; ++j) m[j] = v[j];
  #pragma unroll
  for (int s = 0; s < 5; ++s) {
    int mask = 2 << s;
    #pragma unroll
    for (int j = 0; j < 16; ++j) m[j] = fmaxf(m[j], __shfl_xor(m[j], mask, 64));
  }
  float e[16], ssum[16];
  #pragma unroll
  for (int j = 0; j < 16; ++j) { e[j] = expf(v[j] - m[j]); ssum[j] = e[j]; }
  #pragma unroll
  for (int s = 0; s < 5; ++s) {
    int mask = 2 << s;
    #pragma unroll
    for (int j = 0; j < 16; ++j) ssum[j] += __shfl_xor(ssum[j], mask, 64);
  }
  #pragma unroll
  for (int j = 0; j < 16; ++j) v[j] = e[j] / ssum[j];

  // greedy assignment: 32x (global masked argmax; suppress row+col).
  // Equivalent to the reference peel: each step's b-matrix is one-hot at the
  // global masked argmax (all other entries <= 2nd max <= midpoint -> relu 0),
  // normalized to exactly 1.0 by b/max(b).
  unsigned cmask = 0xFFFFu;  // my 16 columns still active
  int ract = 1;              // my row still active
  unsigned sel = 0;          // selected bits among my 16 cols (at row r0)
  for (int it = 0; it < 32; ++it) {
    float bv = -3.4e38f; int bi = 0;
    if (ract) {
      #pragma unroll
      for (int j = 0; j < 16; ++j) {
        float vv = ((cmask >> j) & 1u) ? v[j] : -3.4e38f;
        if (vv > bv) { bv = vv; bi = base + j; }
      }
    }
    #pragma unroll
    for (int s = 0; s < 6; ++s) {
      int mask = 1 << s;
      float ov = __shfl_xor(bv, mask, 64);
      int   oi = __shfl_xor(bi, mask, 64);
      if (ov > bv || (ov == bv && oi < bi)) { bv = ov; bi = oi; }
    }
    int rr = bi >> 5, cc = bi & 31;
    if (r0 == rr) {
      ract = 0;
      if ((cc >> 4) == hi) sel |= 1u << (cc & 15);
    }
    if ((cc >> 4) == hi) cmask &= ~(1u << (cc & 15));
  }
  // Batch-reversed outputs: image bo uses r[b] (reference: result_centre[::-1]).
  int bo = B - 1 - b;
  #pragma unroll
  for (int j = 0; j < 16; ++j)
    if ((sel >> j) & 1u) src_t[bo * 32 + hi * 16 + j] = r0;
  #pragma unroll
  for (int c = 0; c < 3; ++c) {
    float* dst = out_rc + ((size_t)(bo * 3 + c)) * 1024 + base;
    #pragma unroll
    for (int j = 0; j < 16; ++j) dst[j] = ((sel >> j) & 1u) ? 1.0f : 0.0f;
  }
}

// ---- K2: finish cell sums across 16 channel groups, area argmax, emit perms
__global__ void k2_perm(const float* __restrict__ partial, float* __restrict__ out_perms,
                        int* __restrict__ perm16) {
  __shared__ float cells[16];
  int b = blockIdx.x, t = threadIdx.x;
  if (t < 16) {
    float s = 0.f;
    for (int g = 0; g < 16; ++g) s += partial[(b * 16 + g) * 16 + t];
    cells[t] = s;
  }
  __syncthreads();
  if (t == 0) {
    float s0 = 0.f, s1 = 0.f, s2 = 0.f;
    for (int k = 0; k < 8; ++k)  s0 += cells[k];
    for (int k = 4; k < 12; ++k) s1 += cells[k];
    for (int k = 8; k < 16; ++k) s2 += cells[k];
    int area = 0; float best = s0;
    if (s1 > best) { best = s1; area = 1; }
    if (s2 > best) { area = 2; }
    for (int k = 0; k < 16; ++k) {
      out_perms[b * 16 + k] = (float)c_perm_table[area][k];
      perm16[b * 16 + k]    = c_perm_table[area][k];
    }
  }
}

// ---- K3: whole-image gather copy (float4). One block per (b, c, perm-slot k)
// 112x112 patch. k>=8: identity. k<8: 4 quadrant 56x56 sub-blocks gathered
// from permuted sources per src_t (already batch-reversed).
__global__ void k3_gather(const float* __restrict__ x, float* __restrict__ out,
                          const int* __restrict__ src_t, const int* __restrict__ perm16) {
  __shared__ int qsrc[4];
  __shared__ int obase_s;
  int bid = blockIdx.x;
  int k = bid & 15;
  int c = (bid >> 4) % 3;
  int b = bid / 48;
  int t = threadIdx.x;
  if (t < 4) {
    int tp = perm16[b * 16 + k];
    if (t == 0) obase_s = ((tp >> 2) * 112) * 448 + (tp & 3) * 112;
    int a = t >> 1, bb = t & 1;
    int off;
    if (k >= 8) {
      off = ((tp >> 2) * 112 + a * 56) * 448 + (tp & 3) * 112 + bb * 56;
    } else {
      int mm = ((k >> 2) * 2 + a) * 8 + (k & 3) * 2 + bb;
      int n = src_t[b * 32 + mm];
      int rns = n >> 3, sns = n & 7;
      int kps = (rns >> 1) * 4 + (sns >> 1);
      int tps = perm16[b * 16 + kps];
      off = ((tps >> 2) * 112 + (rns & 1) * 56) * 448 + (tps & 3) * 112 + (sns & 1) * 56;
    }
    qsrc[t] = off;
  }
  __syncthreads();
  size_t base_bc = (size_t)(b * 3 + c) * 200704;
  const float* xs = x + base_bc;
  float* os = out + base_bc + obase_s;
  // 112x112 floats = 3136 float4 (28 per row); all bases are multiples of 56
  // floats -> 16B aligned.
  #pragma unroll
  for (int q = 0; q < 13; ++q) {
    int e = t + q * 256;
    if (e < 3136) {
      int i = e / 28, c4 = e - i * 28;
      int j = c4 * 4;
      int a = (i >= 56), bb = (j >= 56);
      const float4 v = *(const float4*)(xs + qsrc[(a << 1) | bb] + (i - a * 56) * 448 + (j - bb * 56));
      *(float4*)(os + i * 448 + j) = v;
    }
  }
}

extern "C" void kernel_launch(void* const* d_in, const int* in_sizes, int n_in,
                              void* d_out, int out_size, void* d_ws, size_t ws_size,
                              hipStream_t stream) {
  const float* x      = (const float*)d_in[0];
  const float* fea    = (const float*)d_in[1];
  const float* params = (const float*)d_in[2];
  const int*   bseq   = (const int*)d_in[3];
  const int*   bsz    = (const int*)d_in[4];
  float* out = (float*)d_out;

  int B = in_sizes[0] / (3 * 448 * 448);           // 64
  size_t RC_OFF   = (size_t)B * 3 * 448 * 448;     // x_out elements
  size_t PERM_OFF = RC_OFF + (size_t)B * 3 * 32 * 32;

  // d_ws scratch layout (all fully written before read; no zero-init needed)
  float* partial = (float*)d_ws;                        // B*16*16 floats
  int*   src_t   = (int*)d_ws + B * 16 * 16;            // B*32 ints
  int*   perm16  = (int*)d_ws + B * 16 * 16 + B * 32;   // B*16 ints

  hipLaunchKernelGGL(k1_fused, dim3(B * 16 + B), dim3(256), 0, stream,
                     fea, params, bseq, bsz, partial, src_t, out + RC_OFF, B);
  hipLaunchKernelGGL(k2_perm,  dim3(B),          dim3(64),  0, stream,
                     partial, out + PERM_OFF, perm16);
  hipLaunchKernelGGL(k3_gather, dim3(B * 3 * 16), dim3(256), 0, stream,
                     x, out, src_t, perm16);
}

// Round 5
// 125.764 us; speedup vs baseline: 1.9228x; 1.1083x over previous
//
#include <hip/hip_runtime.h>

using f4 = __attribute__((ext_vector_type(4))) float;

__constant__ int c_perm_table[3][16] = {
  {0,1,2,3,4,5,6,7,8,9,10,11,12,13,14,15},
  {4,5,6,7,8,9,10,11,0,1,2,3,12,13,14,15},
  {8,9,10,11,12,13,14,15,0,1,2,3,4,5,6,7}
};

// ---- K1 (fused): blocks [0, B*32) stream fea channel-groups (32 ch each) as
// float4 and reduce to 16 cell sums; blocks [B*32, B*32+B) run the greedy peel.
// Grid: 2048 heavy blocks = exactly 8/CU on 256 CUs (balanced) + 64 cheap.
__global__ void __launch_bounds__(256) k1_fused(
    const float* __restrict__ fea, const float* __restrict__ params,
    const int* __restrict__ pseq, const int* __restrict__ pbsz,
    float* __restrict__ partial, int* __restrict__ src_t,
    float* __restrict__ out_rc, int B) {
  int bid = blockIdx.x;
  if (bid < (B << 5)) {
    // --- fea_map: 32 channels x 784 pixels, contiguous = 6272 float4 ---
    __shared__ float pix[784];
    int b = bid >> 5, g = bid & 31;
    const f4* src4 = (const f4*)(fea + ((size_t)(b * 1024 + g * 32)) * 784);
    int t = threadIdx.x;
    if (t < 196) {
      float ax = 0.f, ay = 0.f, az = 0.f, aw = 0.f;
      #pragma unroll 8
      for (int cc = 0; cc < 32; ++cc) {
        f4 v = src4[cc * 196 + t];
        ax += v.x; ay += v.y; az += v.z; aw += v.w;
      }
      pix[t * 4 + 0] = ax; pix[t * 4 + 1] = ay; pix[t * 4 + 2] = az; pix[t * 4 + 3] = aw;
    }
    __syncthreads();
    if (t < 16) {
      int ci = t >> 2, cj = t & 3;
      float s = 0.f;
      #pragma unroll
      for (int dy = 0; dy < 7; ++dy)
        #pragma unroll
        for (int dx = 0; dx < 7; ++dx)
          s += pix[(ci * 7 + dy) * 28 + cj * 7 + dx];
      partial[(b * 32 + g) * 16 + t] = s;
    }
    return;
  }
  // --- greedy peel: one wave per batch ---
  int b = bid - (B << 5);
  int l = threadIdx.x;
  if (l >= 64) return;
  int start = pseq[0] * pbsz[0];
  int r0 = l >> 1, hi = l & 1;
  int base = r0 * 32 + hi * 16;
  const float* Pp = params + ((size_t)(start + b)) * 1024 + base;
  float v[16];
  #pragma unroll
  for (int j = 0; j < 16; ++j) v[j] = Pp[j];
  // column softmax (reduce over rows = lane bits 1..5)
  float m[16];
  #pragma unroll
  for (int j = 0; j < 16; ++j) m[j] = v[j];
  #pragma unroll
  for (int s = 0; s < 5; ++s) {
    int mask = 2 << s;
    #pragma unroll
    for (int j = 0; j < 16; ++j) m[j] = fmaxf(m[j], __shfl_xor(m[j], mask, 64));
  }
  float e[16], ssum[16];
  #pragma unroll
  for (int j = 0; j < 16; ++j) { e[j] = expf(v[j] - m[j]); ssum[j] = e[j]; }
  #pragma unroll
  for (int s = 0; s < 5; ++s) {
    int mask = 2 << s;
    #pragma unroll
    for (int j = 0; j < 16; ++j) ssum[j] += __shfl_xor(ssum[j], mask, 64);
  }
  #pragma unroll
  for (int j = 0; j < 16; ++j) v[j] = e[j] / ssum[j];

  // greedy assignment: 32x (global masked argmax; suppress row+col).
  // Equivalent to reference peel: each step's b is one-hot at the argmax.
  unsigned cmask = 0xFFFFu;
  int ract = 1;
  unsigned sel = 0;
  for (int it = 0; it < 32; ++it) {
    float bv = -3.4e38f; int bi = 0;
    if (ract) {
      #pragma unroll
      for (int j = 0; j < 16; ++j) {
        float vv = ((cmask >> j) & 1u) ? v[j] : -3.4e38f;
        if (vv > bv) { bv = vv; bi = base + j; }
      }
    }
    #pragma unroll
    for (int s = 0; s < 6; ++s) {
      int mask = 1 << s;
      float ov = __shfl_xor(bv, mask, 64);
      int   oi = __shfl_xor(bi, mask, 64);
      if (ov > bv || (ov == bv && oi < bi)) { bv = ov; bi = oi; }
    }
    int rr = bi >> 5, cc = bi & 31;
    if (r0 == rr) {
      ract = 0;
      if ((cc >> 4) == hi) sel |= 1u << (cc & 15);
    }
    if ((cc >> 4) == hi) cmask &= ~(1u << (cc & 15));
  }
  // Batch-reversed outputs (reference: result_centre[::-1]).
  int bo = B - 1 - b;
  #pragma unroll
  for (int j = 0; j < 16; ++j)
    if ((sel >> j) & 1u) src_t[bo * 32 + hi * 16 + j] = r0;
  #pragma unroll
  for (int c = 0; c < 3; ++c) {
    float* dst = out_rc + ((size_t)(bo * 3 + c)) * 1024 + base;
    #pragma unroll
    for (int j = 0; j < 16; ++j) dst[j] = ((sel >> j) & 1u) ? 1.0f : 0.0f;
  }
}

// ---- K2: finish cell sums across 32 channel groups, area argmax, emit perms
__global__ void k2_perm(const float* __restrict__ partial, float* __restrict__ out_perms,
                        int* __restrict__ perm16) {
  __shared__ float cells[16];
  int b = blockIdx.x, t = threadIdx.x;
  if (t < 16) {
    float s = 0.f;
    for (int g = 0; g < 32; ++g) s += partial[(b * 32 + g) * 16 + t];
    cells[t] = s;
  }
  __syncthreads();
  if (t == 0) {
    float s0 = 0.f, s1 = 0.f, s2 = 0.f;
    for (int k = 0; k < 8; ++k)  s0 += cells[k];
    for (int k = 4; k < 12; ++k) s1 += cells[k];
    for (int k = 8; k < 16; ++k) s2 += cells[k];
    int area = 0; float best = s0;
    if (s1 > best) { best = s1; area = 1; }
    if (s2 > best) { area = 2; }
    for (int k = 0; k < 16; ++k) {
      out_perms[b * 16 + k] = (float)c_perm_table[area][k];
      perm16[b * 16 + k]    = c_perm_table[area][k];
    }
  }
}

// ---- K3: whole-image gather copy (float4, NT stores). One block per
// (b, c, perm-slot k) 112x112 patch. k>=8: identity. k<8: 4 quadrant 56x56
// sub-blocks gathered per src_t (already batch-reversed).
__global__ void __launch_bounds__(256) k3_gather(
    const float* __restrict__ x, float* __restrict__ out,
    const int* __restrict__ src_t, const int* __restrict__ perm16) {
  __shared__ int qsrc[4];
  __shared__ int obase_s;
  int bid = blockIdx.x;
  int k = bid & 15;
  int c = (bid >> 4) % 3;
  int b = bid / 48;
  int t = threadIdx.x;
  if (t < 4) {
    int tp = perm16[b * 16 + k];
    if (t == 0) obase_s = ((tp >> 2) * 112) * 448 + (tp & 3) * 112;
    int a = t >> 1, bb = t & 1;
    int off;
    if (k >= 8) {
      off = ((tp >> 2) * 112 + a * 56) * 448 + (tp & 3) * 112 + bb * 56;
    } else {
      int mm = ((k >> 2) * 2 + a) * 8 + (k & 3) * 2 + bb;
      int n = src_t[b * 32 + mm];
      int rns = n >> 3, sns = n & 7;
      int kps = (rns >> 1) * 4 + (sns >> 1);
      int tps = perm16[b * 16 + kps];
      off = ((tps >> 2) * 112 + (rns & 1) * 56) * 448 + (tps & 3) * 112 + (sns & 1) * 56;
    }
    qsrc[t] = off;
  }
  __syncthreads();
  size_t base_bc = (size_t)(b * 3 + c) * 200704;
  const float* xs = x + base_bc;
  float* os = out + base_bc + obase_s;
  #pragma unroll
  for (int q = 0; q < 13; ++q) {
    int e = t + q * 256;
    if (e < 3136) {
      int i = e / 28, c4 = e - i * 28;
      int j = c4 * 4;
      int a = (i >= 56), bb = (j >= 56);
      f4 v = *(const f4*)(xs + qsrc[(a << 1) | bb] + (i - a * 56) * 448 + (j - bb * 56));
      __builtin_nontemporal_store(v, (f4*)(os + i * 448 + j));
    }
  }
}

extern "C" void kernel_launch(void* const* d_in, const int* in_sizes, int n_in,
                              void* d_out, int out_size, void* d_ws, size_t ws_size,
                              hipStream_t stream) {
  const float* x      = (const float*)d_in[0];
  const float* fea    = (const float*)d_in[1];
  const float* params = (const float*)d_in[2];
  const int*   bseq   = (const int*)d_in[3];
  const int*   bsz    = (const int*)d_in[4];
  float* out = (float*)d_out;

  int B = in_sizes[0] / (3 * 448 * 448);           // 64
  size_t RC_OFF   = (size_t)B * 3 * 448 * 448;     // x_out elements
  size_t PERM_OFF = RC_OFF + (size_t)B * 3 * 32 * 32;

  // d_ws scratch layout (all fully written before read; no zero-init needed)
  float* partial = (float*)d_ws;                        // B*32*16 floats
  int*   src_t   = (int*)d_ws + B * 32 * 16;            // B*32 ints
  int*   perm16  = (int*)d_ws + B * 32 * 16 + B * 32;   // B*16 ints

  hipLaunchKernelGGL(k1_fused, dim3(B * 32 + B), dim3(256), 0, stream,
                     fea, params, bseq, bsz, partial, src_t, out + RC_OFF, B);
  hipLaunchKernelGGL(k2_perm,  dim3(B),          dim3(64),  0, stream,
                     partial, out + PERM_OFF, perm16);
  hipLaunchKernelGGL(k3_gather, dim3(B * 3 * 16), dim3(256), 0, stream,
                     x, out, src_t, perm16);
}

// Round 6
// 118.521 us; speedup vs baseline: 2.0403x; 1.0611x over previous
//
#include <hip/hip_runtime.h>

using f4 = __attribute__((ext_vector_type(4))) float;

__constant__ int c_perm_table[3][16] = {
  {0,1,2,3,4,5,6,7,8,9,10,11,12,13,14,15},
  {4,5,6,7,8,9,10,11,0,1,2,3,12,13,14,15},
  {8,9,10,11,12,13,14,15,0,1,2,3,4,5,6,7}
};

// ---- K1 (fused): blocks [0, B*32) stream fea channel-groups (32 ch each) as
// float4 and reduce to 16 cell partial sums; blocks [B*32, B*32+B) run the
// greedy peel. Grid: 2048 heavy blocks = exactly 8/CU + 64 cheap peel blocks.
__global__ void __launch_bounds__(256) k1_fused(
    const float* __restrict__ fea, const float* __restrict__ params,
    const int* __restrict__ pseq, const int* __restrict__ pbsz,
    float* __restrict__ partial, int* __restrict__ src_t,
    float* __restrict__ out_rc, int B) {
  int bid = blockIdx.x;
  if (bid < (B << 5)) {
    // --- fea_map: 32 channels x 784 pixels, contiguous = 6272 float4 ---
    __shared__ float pix[784];
    int b = bid >> 5, g = bid & 31;
    const f4* src4 = (const f4*)(fea + ((size_t)(b * 1024 + g * 32)) * 784);
    int t = threadIdx.x;
    if (t < 196) {
      float ax = 0.f, ay = 0.f, az = 0.f, aw = 0.f;
      #pragma unroll 8
      for (int cc = 0; cc < 32; ++cc) {
        f4 v = src4[cc * 196 + t];
        ax += v.x; ay += v.y; az += v.z; aw += v.w;
      }
      pix[t * 4 + 0] = ax; pix[t * 4 + 1] = ay; pix[t * 4 + 2] = az; pix[t * 4 + 3] = aw;
    }
    __syncthreads();
    if (t < 16) {
      int ci = t >> 2, cj = t & 3;
      float s = 0.f;
      #pragma unroll
      for (int dy = 0; dy < 7; ++dy)
        #pragma unroll
        for (int dx = 0; dx < 7; ++dx)
          s += pix[(ci * 7 + dy) * 28 + cj * 7 + dx];
      partial[(b * 32 + g) * 16 + t] = s;
    }
    return;
  }
  // --- greedy peel: one wave per batch ---
  int b = bid - (B << 5);
  int l = threadIdx.x;
  if (l >= 64) return;
  int start = pseq[0] * pbsz[0];
  int r0 = l >> 1, hi = l & 1;
  int base = r0 * 32 + hi * 16;
  const float* Pp = params + ((size_t)(start + b)) * 1024 + base;
  float v[16];
  #pragma unroll
  for (int j = 0; j < 16; ++j) v[j] = Pp[j];
  // column softmax (reduce over rows = lane bits 1..5)
  float m[16];
  #pragma unroll
  for (int j = 0; j < 16; ++j) m[j] = v[j];
  #pragma unroll
  for (int s = 0; s < 5; ++s) {
    int mask = 2 << s;
    #pragma unroll
    for (int j = 0; j < 16; ++j) m[j] = fmaxf(m[j], __shfl_xor(m[j], mask, 64));
  }
  float e[16], ssum[16];
  #pragma unroll
  for (int j = 0; j < 16; ++j) { e[j] = expf(v[j] - m[j]); ssum[j] = e[j]; }
  #pragma unroll
  for (int s = 0; s < 5; ++s) {
    int mask = 2 << s;
    #pragma unroll
    for (int j = 0; j < 16; ++j) ssum[j] += __shfl_xor(ssum[j], mask, 64);
  }
  #pragma unroll
  for (int j = 0; j < 16; ++j) v[j] = e[j] / ssum[j];

  // greedy assignment: 32x (global masked argmax; suppress row+col).
  // Equivalent to reference peel: each step's b is one-hot at the argmax.
  unsigned cmask = 0xFFFFu;
  int ract = 1;
  unsigned sel = 0;
  for (int it = 0; it < 32; ++it) {
    float bv = -3.4e38f; int bi = 0;
    if (ract) {
      #pragma unroll
      for (int j = 0; j < 16; ++j) {
        float vv = ((cmask >> j) & 1u) ? v[j] : -3.4e38f;
        if (vv > bv) { bv = vv; bi = base + j; }
      }
    }
    #pragma unroll
    for (int s = 0; s < 6; ++s) {
      int mask = 1 << s;
      float ov = __shfl_xor(bv, mask, 64);
      int   oi = __shfl_xor(bi, mask, 64);
      if (ov > bv || (ov == bv && oi < bi)) { bv = ov; bi = oi; }
    }
    int rr = bi >> 5, cc = bi & 31;
    if (r0 == rr) {
      ract = 0;
      if ((cc >> 4) == hi) sel |= 1u << (cc & 15);
    }
    if ((cc >> 4) == hi) cmask &= ~(1u << (cc & 15));
  }
  // Batch-reversed outputs (reference: result_centre[::-1]).
  int bo = B - 1 - b;
  #pragma unroll
  for (int j = 0; j < 16; ++j)
    if ((sel >> j) & 1u) src_t[bo * 32 + hi * 16 + j] = r0;
  #pragma unroll
  for (int c = 0; c < 3; ++c) {
    float* dst = out_rc + ((size_t)(bo * 3 + c)) * 1024 + base;
    #pragma unroll
    for (int j = 0; j < 16; ++j) dst[j] = ((sel >> j) & 1u) ? 1.0f : 0.0f;
  }
}

// ---- K3 (row-oriented, K2 folded in): one block = 16 full output image rows
// of one (b,c). Output rows (1792B = 14 cache lines) are fully contiguous ->
// no partial-line writes; patch-segment line sharing stays within the wave.
// Setup per block: cells from partial (deterministic), area argmax, perm,
// inverse perm, and the 16 (pc,a,bb) source base offsets.
__global__ void __launch_bounds__(256) k3_rows(
    const float* __restrict__ x, float* __restrict__ out,
    const float* __restrict__ partial, const int* __restrict__ src_t,
    float* __restrict__ out_perms) {
  __shared__ float cells[16];
  __shared__ int perm_s[16];
  __shared__ int inv_s[16];
  __shared__ int off_s[16];
  int bid = blockIdx.x;
  int rg = bid % 28;             // row-group: rows [rg*16, rg*16+16)
  int cch = (bid / 28) % 3;
  int b  = bid / 84;
  int t = threadIdx.x;
  if (t < 16) {
    float s = 0.f;
    #pragma unroll 8
    for (int g = 0; g < 32; ++g) s += partial[(b * 32 + g) * 16 + t];
    cells[t] = s;
  }
  __syncthreads();
  if (t < 16) {
    float s0 = 0.f, s1 = 0.f, s2 = 0.f;
    #pragma unroll
    for (int k = 0; k < 8; ++k)  s0 += cells[k];
    #pragma unroll
    for (int k = 4; k < 12; ++k) s1 += cells[k];
    #pragma unroll
    for (int k = 8; k < 16; ++k) s2 += cells[k];
    int area = 0; float best = s0;
    if (s1 > best) { best = s1; area = 1; }
    if (s2 > best) { area = 2; }
    perm_s[t] = c_perm_table[area][t];
  }
  __syncthreads();
  if (t < 16) inv_s[perm_s[t]] = t;   // bijection
  if (cch == 0 && rg == 0 && t < 16) out_perms[b * 16 + t] = (float)perm_s[t];
  __syncthreads();
  int pr = (rg * 16) / 112;      // patch-row band (block never crosses one)
  if (t < 16) {
    int pc = t >> 2, a = (t >> 1) & 1, bb = t & 1;
    int ppos = pr * 4 + pc;
    int k = inv_s[ppos];
    int off;
    if (k >= 8) {
      off = (pr * 112 + a * 56) * 448 + pc * 112 + bb * 56;   // identity
    } else {
      int rn = (k >> 2) * 2 + a, sn = (k & 3) * 2 + bb;
      int n = src_t[b * 32 + rn * 8 + sn];
      int rns = n >> 3, sns = n & 7;
      int kps = (rns >> 1) * 4 + (sns >> 1);
      int tps = perm_s[kps];
      off = ((tps >> 2) * 112 + (rns & 1) * 56) * 448 + (tps & 3) * 112 + (sns & 1) * 56;
    }
    off_s[t] = off;
  }
  __syncthreads();
  size_t base_bc = (size_t)(b * 3 + cch) * 200704;
  const float* xs = x + base_bc;
  float* os = out + base_bc;
  int y0 = rg * 16;
  int ir0 = y0 % 112;
  #pragma unroll
  for (int p = 0; p < 7; ++p) {
    int idx = p * 256 + t;             // 0..1791 (16 rows x 112 f4)
    int r = idx / 112;
    int c4 = idx - r * 112;
    int ir = ir0 + r;                  // 0..111 within patch band
    int a = ir / 56, irq = ir - a * 56;
    int pc = c4 / 28, c4p = c4 - pc * 28;
    int bb = c4p / 14, jh = c4p - bb * 14;
    int so = off_s[(pc << 2) + (a << 1) + bb] + irq * 448 + jh * 4;
    f4 v = *(const f4*)(xs + so);
    __builtin_nontemporal_store(v, (f4*)(os + (y0 + r) * 448 + c4 * 4));
  }
}

extern "C" void kernel_launch(void* const* d_in, const int* in_sizes, int n_in,
                              void* d_out, int out_size, void* d_ws, size_t ws_size,
                              hipStream_t stream) {
  const float* x      = (const float*)d_in[0];
  const float* fea    = (const float*)d_in[1];
  const float* params = (const float*)d_in[2];
  const int*   bseq   = (const int*)d_in[3];
  const int*   bsz    = (const int*)d_in[4];
  float* out = (float*)d_out;

  int B = in_sizes[0] / (3 * 448 * 448);           // 64
  size_t RC_OFF   = (size_t)B * 3 * 448 * 448;     // x_out elements
  size_t PERM_OFF = RC_OFF + (size_t)B * 3 * 32 * 32;

  // d_ws scratch (fully written before read; no zero-init needed)
  float* partial = (float*)d_ws;                        // B*32*16 floats
  int*   src_t   = (int*)d_ws + B * 32 * 16;            // B*32 ints

  hipLaunchKernelGGL(k1_fused, dim3(B * 32 + B), dim3(256), 0, stream,
                     fea, params, bseq, bsz, partial, src_t, out + RC_OFF, B);
  hipLaunchKernelGGL(k3_rows, dim3(B * 3 * 28), dim3(256), 0, stream,
                     x, out, partial, src_t, out + PERM_OFF);
}

// Round 7
// 83.637 us; speedup vs baseline: 2.8913x; 1.4171x over previous
//
#include <hip/hip_runtime.h>

using f4 = __attribute__((ext_vector_type(4))) float;

__constant__ int c_perm_table[3][16] = {
  {0,1,2,3,4,5,6,7,8,9,10,11,12,13,14,15},
  {4,5,6,7,8,9,10,11,0,1,2,3,12,13,14,15},
  {8,9,10,11,12,13,14,15,0,1,2,3,4,5,6,7}
};

// ---- K1 (fused): blocks [0,B) run the greedy peel (dispatched FIRST so they
// are hidden under the streaming blocks); blocks [B, B + B*16) stream fea
// channel-groups (2 groups of 32 ch each = 784 KB/block) as NT float4 loads.
// Grid: 64 + 1024 = 1088 blocks, all co-resident (8 slots/CU) -> no tail.
__global__ void __launch_bounds__(256) k1_fused(
    const float* __restrict__ fea, const float* __restrict__ params,
    const int* __restrict__ pseq, const int* __restrict__ pbsz,
    float* __restrict__ partial, int* __restrict__ src_t,
    float* __restrict__ out_rc, int B) {
  int bid = blockIdx.x;
  if (bid >= B) {
    // --- fea_map: 2 channel-groups x (32 ch x 784 px contiguous) ---
    __shared__ float pix[784];
    int hb = bid - B;
    int b = hb >> 4, gpair = hb & 15;
    int t = threadIdx.x;
    #pragma unroll
    for (int half = 0; half < 2; ++half) {
      int g = gpair * 2 + half;
      const f4* src4 = (const f4*)(fea + ((size_t)(b * 1024 + g * 32)) * 784);
      if (t < 196) {
        float ax = 0.f, ay = 0.f, az = 0.f, aw = 0.f;
        #pragma unroll 8
        for (int cc = 0; cc < 32; ++cc) {
          f4 v = __builtin_nontemporal_load(&src4[cc * 196 + t]);
          ax += v.x; ay += v.y; az += v.z; aw += v.w;
        }
        pix[t * 4 + 0] = ax; pix[t * 4 + 1] = ay; pix[t * 4 + 2] = az; pix[t * 4 + 3] = aw;
      }
      __syncthreads();
      if (t < 16) {
        int ci = t >> 2, cj = t & 3;
        float s = 0.f;
        #pragma unroll
        for (int dy = 0; dy < 7; ++dy)
          #pragma unroll
          for (int dx = 0; dx < 7; ++dx)
            s += pix[(ci * 7 + dy) * 28 + cj * 7 + dx];
        partial[(b * 32 + g) * 16 + t] = s;
      }
      __syncthreads();
    }
    return;
  }
  // --- greedy peel: one wave per batch, blocks 0..B-1 (start immediately) ---
  int b = bid;
  int l = threadIdx.x;
  if (l >= 64) return;
  int start = pseq[0] * pbsz[0];
  int r0 = l >> 1, hi = l & 1;
  int base = r0 * 32 + hi * 16;
  const float* Pp = params + ((size_t)(start + b)) * 1024 + base;
  float v[16];
  #pragma unroll
  for (int j = 0; j < 16; ++j) v[j] = Pp[j];
  // column softmax (reduce over rows = lane bits 1..5)
  float m[16];
  #pragma unroll
  for (int j = 0; j < 16; ++j) m[j] = v[j];
  #pragma unroll
  for (int s = 0; s < 5; ++s) {
    int mask = 2 << s;
    #pragma unroll
    for (int j = 0; j < 16; ++j) m[j] = fmaxf(m[j], __shfl_xor(m[j], mask, 64));
  }
  float e[16], ssum[16];
  #pragma unroll
  for (int j = 0; j < 16; ++j) { e[j] = expf(v[j] - m[j]); ssum[j] = e[j]; }
  #pragma unroll
  for (int s = 0; s < 5; ++s) {
    int mask = 2 << s;
    #pragma unroll
    for (int j = 0; j < 16; ++j) ssum[j] += __shfl_xor(ssum[j], mask, 64);
  }
  #pragma unroll
  for (int j = 0; j < 16; ++j) v[j] = e[j] / ssum[j];

  // greedy assignment: 32x (global masked argmax; suppress row+col).
  // Equivalent to reference peel: each step's b is one-hot at the argmax.
  unsigned cmask = 0xFFFFu;
  int ract = 1;
  unsigned sel = 0;
  for (int it = 0; it < 32; ++it) {
    float bv = -3.4e38f; int bi = 0;
    if (ract) {
      #pragma unroll
      for (int j = 0; j < 16; ++j) {
        float vv = ((cmask >> j) & 1u) ? v[j] : -3.4e38f;
        if (vv > bv) { bv = vv; bi = base + j; }
      }
    }
    #pragma unroll
    for (int s = 0; s < 6; ++s) {
      int mask = 1 << s;
      float ov = __shfl_xor(bv, mask, 64);
      int   oi = __shfl_xor(bi, mask, 64);
      if (ov > bv || (ov == bv && oi < bi)) { bv = ov; bi = oi; }
    }
    int rr = bi >> 5, cc = bi & 31;
    if (r0 == rr) {
      ract = 0;
      if ((cc >> 4) == hi) sel |= 1u << (cc & 15);
    }
    if ((cc >> 4) == hi) cmask &= ~(1u << (cc & 15));
  }
  // Batch-reversed outputs (reference: result_centre[::-1]).
  int bo = B - 1 - b;
  #pragma unroll
  for (int j = 0; j < 16; ++j)
    if ((sel >> j) & 1u) src_t[bo * 32 + hi * 16 + j] = r0;
  #pragma unroll
  for (int c = 0; c < 3; ++c) {
    float* dst = out_rc + ((size_t)(bo * 3 + c)) * 1024 + base;
    #pragma unroll
    for (int j = 0; j < 16; ++j) dst[j] = ((sel >> j) & 1u) ? 1.0f : 0.0f;
  }
}

// ---- K3 (row-oriented, K2 folded in, XCD-swizzled): one block = 16 full
// output image rows of one (b,c). Output rows (1792B = 14 lines) contiguous;
// XCD-chunked swizzle keeps all 84 blocks of an image on one XCD so the
// 224B-chunk line splits are de-duplicated by that XCD's L2.
__global__ void __launch_bounds__(256) k3_rows(
    const float* __restrict__ x, float* __restrict__ out,
    const float* __restrict__ partial, const int* __restrict__ src_t,
    float* __restrict__ out_perms, int nwg) {
  __shared__ float cells[16];
  __shared__ int perm_s[16];
  __shared__ int inv_s[16];
  __shared__ int off_s[16];
  // bijective XCD swizzle: nwg % 8 == 0 (5376 = 8*672)
  int cpx = nwg >> 3;
  int bid0 = blockIdx.x;
  int bid = (bid0 % 8) * cpx + bid0 / 8;
  int rg = bid % 28;             // row-group: rows [rg*16, rg*16+16)
  int cch = (bid / 28) % 3;
  int b  = bid / 84;
  int t = threadIdx.x;
  if (t < 16) {
    float s = 0.f;
    #pragma unroll 8
    for (int g = 0; g < 32; ++g) s += partial[(b * 32 + g) * 16 + t];
    cells[t] = s;
  }
  __syncthreads();
  if (t < 16) {
    float s0 = 0.f, s1 = 0.f, s2 = 0.f;
    #pragma unroll
    for (int k = 0; k < 8; ++k)  s0 += cells[k];
    #pragma unroll
    for (int k = 4; k < 12; ++k) s1 += cells[k];
    #pragma unroll
    for (int k = 8; k < 16; ++k) s2 += cells[k];
    int area = 0; float best = s0;
    if (s1 > best) { best = s1; area = 1; }
    if (s2 > best) { area = 2; }
    perm_s[t] = c_perm_table[area][t];
  }
  __syncthreads();
  if (t < 16) inv_s[perm_s[t]] = t;   // bijection
  if (cch == 0 && rg == 0 && t < 16) out_perms[b * 16 + t] = (float)perm_s[t];
  __syncthreads();
  int pr = (rg * 16) / 112;      // patch-row band (block never crosses one)
  if (t < 16) {
    int pc = t >> 2, a = (t >> 1) & 1, bb = t & 1;
    int ppos = pr * 4 + pc;
    int k = inv_s[ppos];
    int off;
    if (k >= 8) {
      off = (pr * 112 + a * 56) * 448 + pc * 112 + bb * 56;   // identity
    } else {
      int rn = (k >> 2) * 2 + a, sn = (k & 3) * 2 + bb;
      int n = src_t[b * 32 + rn * 8 + sn];
      int rns = n >> 3, sns = n & 7;
      int kps = (rns >> 1) * 4 + (sns >> 1);
      int tps = perm_s[kps];
      off = ((tps >> 2) * 112 + (rns & 1) * 56) * 448 + (tps & 3) * 112 + (sns & 1) * 56;
    }
    off_s[t] = off;
  }
  __syncthreads();
  size_t base_bc = (size_t)(b * 3 + cch) * 200704;
  const float* xs = x + base_bc;
  float* os = out + base_bc;
  int y0 = rg * 16;
  int ir0 = y0 % 112;
  #pragma unroll
  for (int p = 0; p < 7; ++p) {
    int idx = p * 256 + t;             // 0..1791 (16 rows x 112 f4)
    int r = idx / 112;
    int c4 = idx - r * 112;
    int ir = ir0 + r;                  // 0..111 within patch band
    int a = ir / 56, irq = ir - a * 56;
    int pc = c4 / 28, c4p = c4 - pc * 28;
    int bb = c4p / 14, jh = c4p - bb * 14;
    int so = off_s[(pc << 2) + (a << 1) + bb] + irq * 448 + jh * 4;
    f4 v = *(const f4*)(xs + so);
    __builtin_nontemporal_store(v, (f4*)(os + (y0 + r) * 448 + c4 * 4));
  }
}

extern "C" void kernel_launch(void* const* d_in, const int* in_sizes, int n_in,
                              void* d_out, int out_size, void* d_ws, size_t ws_size,
                              hipStream_t stream) {
  const float* x      = (const float*)d_in[0];
  const float* fea    = (const float*)d_in[1];
  const float* params = (const float*)d_in[2];
  const int*   bseq   = (const int*)d_in[3];
  const int*   bsz    = (const int*)d_in[4];
  float* out = (float*)d_out;

  int B = in_sizes[0] / (3 * 448 * 448);           // 64
  size_t RC_OFF   = (size_t)B * 3 * 448 * 448;     // x_out elements
  size_t PERM_OFF = RC_OFF + (size_t)B * 3 * 32 * 32;

  // d_ws scratch (fully written before read; no zero-init needed)
  float* partial = (float*)d_ws;                        // B*32*16 floats
  int*   src_t   = (int*)d_ws + B * 32 * 16;            // B*32 ints

  int nwg3 = B * 3 * 28;                                // 5376, % 8 == 0
  hipLaunchKernelGGL(k1_fused, dim3(B + B * 16), dim3(256), 0, stream,
                     fea, params, bseq, bsz, partial, src_t, out + RC_OFF, B);
  hipLaunchKernelGGL(k3_rows, dim3(nwg3), dim3(256), 0, stream,
                     x, out, partial, src_t, out + PERM_OFF, nwg3);
}